// Round 14
// baseline (386.835 us; speedup 1.0000x reference)
//
#include <hip/hip_runtime.h>
#include <hip/hip_bf16.h>
#include <math.h>

#define TOKENS 8192
#define Dm 768
#define Fm 3072
#define Em 8
#define BK 64
#define MT_MAX 136   // max sum of ceil(cnt_e/128): 16384/128 + 8

typedef __attribute__((ext_vector_type(8))) short short8v;
typedef __attribute__((ext_vector_type(4))) short short4v;
typedef __attribute__((ext_vector_type(4))) float f32x4;

__device__ inline short f2b(float f) {
  __hip_bfloat16 h = __float2bfloat16(f);
  return *reinterpret_cast<short*>(&h);
}

__device__ inline void async16(short* lds, const short* g) {
  __builtin_amdgcn_global_load_lds((const __attribute__((address_space(1))) void*)g,
                                   (__attribute__((address_space(3))) void*)lds, 16, 0, 0);
}

// ------------- transpose + convert: in f32 [R][C] -> out bf16 [C][R], per expert (z) -------------
__global__ __launch_bounds__(256) void cvt_tr_kernel(const float* __restrict__ in,
                                                     short* __restrict__ out, int R, int C) {
  __shared__ short tile[64][68];
  size_t eoff = (size_t)blockIdx.z * R * C;
  const float* inp = in + eoff;
  short* outp = out + eoff;
  int tc = blockIdx.x * 64, tr = blockIdx.y * 64;
  {
    int row = threadIdx.x >> 2;
    int cch = (threadIdx.x & 3) * 16;
    const float* src = inp + (size_t)(tr + row) * C + tc + cch;
    #pragma unroll
    for (int q = 0; q < 4; q++) {
      float4 v = *(const float4*)(src + q * 4);
      tile[row][cch + q * 4 + 0] = f2b(v.x);
      tile[row][cch + q * 4 + 1] = f2b(v.y);
      tile[row][cch + q * 4 + 2] = f2b(v.z);
      tile[row][cch + q * 4 + 3] = f2b(v.w);
    }
  }
  __syncthreads();
  {
    int c = threadIdx.x >> 2;
    int rch = (threadIdx.x & 3) * 16;
    short tmp[16];
    #pragma unroll
    for (int i = 0; i < 16; i++) tmp[i] = tile[rch + i][c];
    short* dst = outp + (size_t)(tc + c) * R + tr + rch;
    *(short8v*)(dst) = *(short8v*)(tmp);
    *(short8v*)(dst + 8) = *(short8v*)(tmp + 8);
  }
}

// ---------------- router: top-2 + x->bf16 + out init = p0*b2[e0]+p1*b2[e1]; NO atomics ----------------
__global__ __launch_bounds__(256) void router_kernel(
    const float* __restrict__ x, const float* __restrict__ rw,
    const float* __restrict__ rb, const float* __restrict__ b2,
    short* __restrict__ xb, float* __restrict__ out,
    int2* __restrict__ meta_e, float2* __restrict__ meta_p) {
  int wave = threadIdx.x >> 6;
  int lane = threadIdx.x & 63;
  int t = blockIdx.x * 4 + wave;
  if (t >= TOKENS) return;
  const float* xr = x + (size_t)t * Dm;
  short* xbr = xb + (size_t)t * Dm;
  float acc[Em];
  #pragma unroll
  for (int e = 0; e < Em; e++) acc[e] = 0.f;
  #pragma unroll
  for (int i = 0; i < 3; i++) {
    int d = i * 256 + lane * 4;
    float4 v = *(const float4*)(xr + d);
    short4v s;
    s[0] = f2b(v.x); s[1] = f2b(v.y); s[2] = f2b(v.z); s[3] = f2b(v.w);
    *(short4v*)(xbr + d) = s;
    #pragma unroll
    for (int j = 0; j < 4; j++) {
      float xv = (j == 0) ? v.x : (j == 1) ? v.y : (j == 2) ? v.z : v.w;
      const float4* rwp = (const float4*)(rw + (size_t)(d + j) * Em);
      float4 a = rwp[0], b = rwp[1];
      acc[0] += xv * a.x; acc[1] += xv * a.y; acc[2] += xv * a.z; acc[3] += xv * a.w;
      acc[4] += xv * b.x; acc[5] += xv * b.y; acc[6] += xv * b.z; acc[7] += xv * b.w;
    }
  }
  #pragma unroll
  for (int e = 0; e < Em; e++) {
    float v = acc[e];
    #pragma unroll
    for (int s = 32; s > 0; s >>= 1) v += __shfl_xor(v, s);
    acc[e] = v + rb[e];
  }
  int i1 = 0; float m1 = acc[0];
  #pragma unroll
  for (int e = 1; e < Em; e++) if (acc[e] > m1) { m1 = acc[e]; i1 = e; }
  int i2 = -1; float m2 = -1e30f;
  #pragma unroll
  for (int e = 0; e < Em; e++) if (e != i1 && acc[e] > m2) { m2 = acc[e]; i2 = e; }
  float tt = expf(m2 - m1);
  float p0 = 1.f / (1.f + tt);
  float p1 = tt / (1.f + tt);
  // out init (every launch — harness does not re-poison between replays)
  const float4* ba = (const float4*)(b2 + (size_t)i1 * Dm);
  const float4* bb = (const float4*)(b2 + (size_t)i2 * Dm);
  float4* orow = (float4*)(out + (size_t)t * Dm);
  #pragma unroll
  for (int i = 0; i < 3; i++) {
    int idx = lane + 64 * i;
    float4 a = ba[idx], b = bb[idx];
    float4 o;
    o.x = p0 * a.x + p1 * b.x; o.y = p0 * a.y + p1 * b.y;
    o.z = p0 * a.z + p1 * b.z; o.w = p0 * a.w + p1 * b.w;
    orow[idx] = o;
  }
  if (lane == 0) {
    meta_e[t] = make_int2(i1, i2);
    meta_p[t] = make_float2(p0, p1);
  }
}

// ---------------- scatter: hierarchical (LDS ranks + 8 global atomics/block) ----------------
__global__ __launch_bounds__(256) void scatter_kernel(
    const int2* __restrict__ meta_e, const float2* __restrict__ meta_p,
    int* __restrict__ cnt, int* __restrict__ list, float* __restrict__ wlist) {
  __shared__ int lcnt[Em];
  __shared__ int gbase[Em];
  int t = blockIdx.x * 256 + threadIdx.x;
  if (threadIdx.x < Em) lcnt[threadIdx.x] = 0;
  __syncthreads();
  int2 e = meta_e[t];
  float2 p = meta_p[t];
  int r0 = atomicAdd(&lcnt[e.x], 1);
  int r1 = atomicAdd(&lcnt[e.y], 1);
  __syncthreads();
  if (threadIdx.x < Em) gbase[threadIdx.x] = atomicAdd(&cnt[threadIdx.x], lcnt[threadIdx.x]);
  __syncthreads();
  int s0 = gbase[e.x] + r0;
  int s1 = gbase[e.y] + r1;
  list[e.x * TOKENS + s0] = t;  wlist[e.x * TOKENS + s0] = p.x;
  list[e.y * TOKENS + s1] = t;  wlist[e.y * TOKENS + s1] = p.y;
}

// ---------------- prefix + compact tile table (BM=128) ----------------
__global__ void prefix_kernel(const int* __restrict__ cnt, int* __restrict__ hoffs,
                              int2* __restrict__ table, int* __restrict__ ntab) {
  if (threadIdx.x == 0) {
    int s = 0, k = 0;
    for (int e = 0; e < Em; e++) {
      hoffs[e] = s;
      int c = cnt[e];
      for (int mb = 0; mb < c; mb += 128) table[k++] = make_int2(e, mb);
      s += c;
    }
    ntab[0] = k;
  }
}

// ---- grouped GEMM 128x128xBK64: counted-vmcnt dbuf schedule, 65KB LDS -> 2 blocks/CU ----
// MODE 0: h[slot] = gelu(x[tok] @ w1t^T + b1)   MODE 1: out[tok] += p * (h[slot] @ w2t^T)
// NOTE: min-waves/EU stays 2 — higher values cap VGPR and spill acc (R11: 2.04GB scratch traffic).
template <int MODE, int NB>
__global__ __launch_bounds__(256, 2) void moe_gemm_kernel(
    const short* __restrict__ Abase, const short* __restrict__ Wt,
    const float* __restrict__ bias, short* __restrict__ Hout,
    float* __restrict__ Out, const int* __restrict__ cnt,
    const int* __restrict__ hoffs, const int* __restrict__ list,
    const float* __restrict__ wlist, const int2* __restrict__ table,
    const int* __restrict__ ntab, int Ndim, int Kdim) {
  // XCD-chunked bijective remap (m204), n-OUTER: consecutive wg within an XCD chunk
  // share the SAME n-tile (B weight panel, 197KB-786KB << 4MB XCD-L2) and walk m-tiles.
  // B staging loads become L2 hits; m-tile-shared order thrashed L2 (R13: 4.7-13MB demand).
  int nwg = gridDim.x;
  int orig = blockIdx.x;
  int q8 = nwg >> 3, r8 = nwg & 7, xcd = orig & 7;
  int wg = (xcd < r8 ? xcd * (q8 + 1) : r8 * (q8 + 1) + (xcd - r8) * q8) + (orig >> 3);
  int ntt = ntab[0];
  int nt = wg / ntt;
  if (nt >= NB) return;
  int ti = wg - nt * ntt;
  int2 te = table[ti];
  int e = te.x, mbase = te.y;
  int count = cnt[e], ho = hoffs[e];
  int n0 = nt * 128;

  __shared__ short As[2][128 * 64];   // 32 KiB total
  __shared__ short Bs[2][128 * 64];   // 32 KiB total  -> 65 KiB/block -> 2 blocks/CU
  __shared__ int rid_s[128];
  __shared__ float pw_s[128];

  int tid = threadIdx.x;
  if (tid < 128) {
    int rc = mbase + tid; if (rc > count - 1) rc = count - 1;
    rid_s[tid] = list[e * TOKENS + rc];
    pw_s[tid] = wlist[e * TOKENS + rc];
  }
  __syncthreads();

  // stage pointers: pass q covers rows q*32+(tid>>3); source granule pre-swizzled g ^= row&7
  const short* We = Wt + (size_t)e * Ndim * Kdim;
  const short* aptr[4];
  const short* bptr[4];
  #pragma unroll
  for (int q = 0; q < 4; q++) {
    int r = q * 32 + (tid >> 3);
    int g = (tid & 7) ^ (r & 7);
    size_t grow;
    if (MODE == 0) {
      grow = (size_t)rid_s[r] * Kdim;              // gathered token row in xbf
    } else {
      int rr = mbase + r; if (rr > count - 1) rr = count - 1;
      grow = (size_t)(ho + rr) * Kdim;             // contiguous slot row in h
    }
    aptr[q] = Abase + grow + g * 8;
    bptr[q] = We + (size_t)(n0 + r) * Kdim + g * 8;
  }
  int w = tid >> 6;

  #define STAGE(s)                                             \
    {                                                          \
      _Pragma("unroll")                                        \
      for (int q = 0; q < 4; q++) {                            \
        async16(&As[s][q * 2048 + w * 512], aptr[q]); aptr[q] += BK; \
        async16(&Bs[s][q * 2048 + w * 512], bptr[q]); bptr[q] += BK; \
      }                                                        \
    }

  int NT = Kdim / BK;
  f32x4 acc[4][4] = {};
  int lane = tid & 63;
  int wm = w >> 1, wn = w & 1;          // 2x2 waves, 64x64 output each
  int lr = lane & 15, lh = lane >> 4;
  int rsw = lr & 7;

  // prologue: two tiles in flight (R6-verified)
  STAGE(0);
  STAGE(1);
  asm volatile("s_waitcnt vmcnt(8)" ::: "memory");   // tile 0's 8 loads landed (mine)
  __builtin_amdgcn_s_barrier();

  for (int t = 0; t < NT; t++) {
    int s = t & 1;
    const short* Ab = As[s];
    const short* Bb = Bs[s];
    // kk0 fragments
    short8v a0[4], b0[4];
    #pragma unroll
    for (int m = 0; m < 4; m++)
      a0[m] = *(const short8v*)&Ab[(wm * 64 + m * 16 + lr) * 64 + (lh ^ rsw) * 8];
    #pragma unroll
    for (int n = 0; n < 4; n++)
      b0[n] = *(const short8v*)&Bb[(wn * 64 + n * 16 + lr) * 64 + (lh ^ rsw) * 8];
    __builtin_amdgcn_s_setprio(1);
    #pragma unroll
    for (int m = 0; m < 4; m++)
      #pragma unroll
      for (int n = 0; n < 4; n++)
        acc[m][n] = __builtin_amdgcn_mfma_f32_16x16x32_bf16(a0[m], b0[n], acc[m][n], 0, 0, 0);
    __builtin_amdgcn_s_setprio(0);
    // kk1 fragments (into registers BEFORE slot s is recycled)
    short8v a1[4], b1v[4];
    #pragma unroll
    for (int m = 0; m < 4; m++)
      a1[m] = *(const short8v*)&Ab[(wm * 64 + m * 16 + lr) * 64 + ((4 + lh) ^ rsw) * 8];
    #pragma unroll
    for (int n = 0; n < 4; n++)
      b1v[n] = *(const short8v*)&Bb[(wn * 64 + n * 16 + lr) * 64 + ((4 + lh) ^ rsw) * 8];
    // all slot-s reads complete; barrier => every wave done with slot s
    asm volatile("s_waitcnt lgkmcnt(0)" ::: "memory");
    __builtin_amdgcn_sched_barrier(0);
    __builtin_amdgcn_s_barrier();
    if (t + 2 < NT) STAGE(s);         // overwrite slot s with tile t+2 (registers hold kk1)
    __builtin_amdgcn_s_setprio(1);
    #pragma unroll
    for (int m = 0; m < 4; m++)
      #pragma unroll
      for (int n = 0; n < 4; n++)
        acc[m][n] = __builtin_amdgcn_mfma_f32_16x16x32_bf16(a1[m], b1v[n], acc[m][n], 0, 0, 0);
    __builtin_amdgcn_s_setprio(0);
    if (t + 2 < NT)
      asm volatile("s_waitcnt vmcnt(8)" ::: "memory");   // tile t+1's batch landed (mine)
    else
      asm volatile("s_waitcnt vmcnt(0)" ::: "memory");
    __builtin_amdgcn_s_barrier();     // all waves landed tile t+1 => safe to read next
  }
  #undef STAGE

  // ---------------- epilogue ----------------
  if (MODE == 0) {
    const float* be = bias + (size_t)e * Ndim;
    #pragma unroll
    for (int m = 0; m < 4; m++) {
      #pragma unroll
      for (int j = 0; j < 4; j++) {
        int r = wm * 64 + m * 16 + lh * 4 + j;
        if (mbase + r < count) {
          size_t rowoff = (size_t)(ho + mbase + r) * Ndim;
          #pragma unroll
          for (int n = 0; n < 4; n++) {
            int colg = n0 + wn * 64 + n * 16 + lr;
            float val = acc[m][n][j] + be[colg];
            // tanh-form gelu via sigmoid: gelu(x) = x / (1 + exp2(x*(c1 + c2*x^2)))
            // c1 = -2*log2(e)*sqrt(2/pi), c2 = c1*0.044715. |err| vs exact ~3e-4.
            // 7 VALU inst vs ~22 for A&S erf (R13: gelu epilogue was ~56us of VALU).
            float x2 = val * val;
            float ex = exp2f(val * fmaf(x2, -0.1029432f, -2.3022082f));
            val = __fdividef(val, 1.f + ex);
            Hout[rowoff + colg] = f2b(val);
          }
        }
      }
    }
  } else {
    #pragma unroll
    for (int m = 0; m < 4; m++) {
      #pragma unroll
      for (int j = 0; j < 4; j++) {
        int r = wm * 64 + m * 16 + lh * 4 + j;
        if (mbase + r < count) {
          float* orow = Out + (size_t)rid_s[r] * Dm;
          float p = pw_s[r];
          #pragma unroll
          for (int n = 0; n < 4; n++) {
            int colg = n0 + wn * 64 + n * 16 + lr;
            atomicAdd(&orow[colg], p * acc[m][n][j]);
          }
        }
      }
    }
  }
}

// ---------------- host ----------------
extern "C" void kernel_launch(void* const* d_in, const int* in_sizes, int n_in,
                              void* d_out, int out_size, void* d_ws, size_t ws_size,
                              hipStream_t stream) {
  const float* x  = (const float*)d_in[0];
  const float* rw = (const float*)d_in[1];
  const float* rb = (const float*)d_in[2];
  const float* w1 = (const float*)d_in[3];
  const float* b1 = (const float*)d_in[4];
  const float* w2 = (const float*)d_in[5];
  const float* b2 = (const float*)d_in[6];
  float* out = (float*)d_out;
  char* ws = (char*)d_ws;

  const size_t off_cnt    = 0;      // 32 B
  const size_t off_hoffs  = 64;     // 32 B
  const size_t off_ntab   = 128;    // 4 B
  const size_t off_table  = 192;    // 136*8 B
  const size_t off_list   = 2048;                                   // E*T*4 = 256K
  const size_t off_wlist  = off_list + (size_t)Em * TOKENS * 4;     // 256K
  const size_t off_meta_e = off_wlist + (size_t)Em * TOKENS * 4;
  const size_t off_meta_p = off_meta_e + (size_t)TOKENS * 8;
  const size_t off_xbf    = off_meta_p + (size_t)TOKENS * 8;
  const size_t off_w1t    = off_xbf + (size_t)TOKENS * Dm * 2;      // 12.6M
  const size_t off_w2t    = off_w1t + (size_t)Em * Dm * Fm * 2;     // +37.7M
  const size_t off_h      = off_w2t + (size_t)Em * Fm * Dm * 2;     // +37.7M
  const size_t needed     = off_h + (size_t)2 * TOKENS * Fm * 2;    // +100.7M
  if (ws_size < needed) return;

  int*    cnt    = (int*)(ws + off_cnt);
  int*    hoffs  = (int*)(ws + off_hoffs);
  int*    ntab   = (int*)(ws + off_ntab);
  int2*   table  = (int2*)(ws + off_table);
  int*    list   = (int*)(ws + off_list);
  float*  wlist  = (float*)(ws + off_wlist);
  int2*   meta_e = (int2*)(ws + off_meta_e);
  float2* meta_p = (float2*)(ws + off_meta_p);
  short*  xbf    = (short*)(ws + off_xbf);
  short*  w1t    = (short*)(ws + off_w1t);
  short*  w2t    = (short*)(ws + off_w2t);
  short*  h      = (short*)(ws + off_h);

  hipMemsetAsync(cnt, 0, 32, stream);
  cvt_tr_kernel<<<dim3(Fm / 64, Dm / 64, Em), 256, 0, stream>>>(w1, w1t, Dm, Fm);
  cvt_tr_kernel<<<dim3(Dm / 64, Fm / 64, Em), 256, 0, stream>>>(w2, w2t, Fm, Dm);
  router_kernel<<<TOKENS / 4, 256, 0, stream>>>(x, rw, rb, b2, xbf, out, meta_e, meta_p);
  scatter_kernel<<<TOKENS / 256, 256, 0, stream>>>(meta_e, meta_p, cnt, list, wlist);
  prefix_kernel<<<1, 64, 0, stream>>>(cnt, hoffs, table, ntab);
  moe_gemm_kernel<0, Fm / 128><<<MT_MAX * (Fm / 128), 256, 0, stream>>>(
      xbf, w1t, b1, h, nullptr, cnt, hoffs, list, wlist, table, ntab, Fm, Dm);
  moe_gemm_kernel<1, Dm / 128><<<MT_MAX * (Dm / 128), 256, 0, stream>>>(
      h, w2t, nullptr, nullptr, out, cnt, hoffs, list, wlist, table, ntab, Dm, Fm);
}

// Round 16
// 358.524 us; speedup vs baseline: 1.0790x; 1.0790x over previous
//
#include <hip/hip_runtime.h>
#include <hip/hip_bf16.h>
#include <math.h>

#define TOKENS 8192
#define Dm 768
#define Fm 3072
#define Em 8
#define BK 64
#define MT_MAX 136   // max sum of ceil(cnt_e/128): 16384/128 + 8

typedef __attribute__((ext_vector_type(8))) short short8v;
typedef __attribute__((ext_vector_type(4))) short short4v;
typedef __attribute__((ext_vector_type(4))) float f32x4;

__device__ inline short f2b(float f) {
  __hip_bfloat16 h = __float2bfloat16(f);
  return *reinterpret_cast<short*>(&h);
}

__device__ inline void async16(short* lds, const short* g) {
  __builtin_amdgcn_global_load_lds((const __attribute__((address_space(1))) void*)g,
                                   (__attribute__((address_space(3))) void*)lds, 16, 0, 0);
}

// ------------- transpose + convert: in f32 [R][C] -> out bf16 [C][R], per expert (z) -------------
__global__ __launch_bounds__(256) void cvt_tr_kernel(const float* __restrict__ in,
                                                     short* __restrict__ out, int R, int C) {
  __shared__ short tile[64][68];
  size_t eoff = (size_t)blockIdx.z * R * C;
  const float* inp = in + eoff;
  short* outp = out + eoff;
  int tc = blockIdx.x * 64, tr = blockIdx.y * 64;
  {
    int row = threadIdx.x >> 2;
    int cch = (threadIdx.x & 3) * 16;
    const float* src = inp + (size_t)(tr + row) * C + tc + cch;
    #pragma unroll
    for (int q = 0; q < 4; q++) {
      float4 v = *(const float4*)(src + q * 4);
      tile[row][cch + q * 4 + 0] = f2b(v.x);
      tile[row][cch + q * 4 + 1] = f2b(v.y);
      tile[row][cch + q * 4 + 2] = f2b(v.z);
      tile[row][cch + q * 4 + 3] = f2b(v.w);
    }
  }
  __syncthreads();
  {
    int c = threadIdx.x >> 2;
    int rch = (threadIdx.x & 3) * 16;
    short tmp[16];
    #pragma unroll
    for (int i = 0; i < 16; i++) tmp[i] = tile[rch + i][c];
    short* dst = outp + (size_t)(tc + c) * R + tr + rch;
    *(short8v*)(dst) = *(short8v*)(tmp);
    *(short8v*)(dst + 8) = *(short8v*)(tmp + 8);
  }
}

// ---------------- router: top-2 + x->bf16 + out init = p0*b2[e0]+p1*b2[e1]; NO atomics ----------------
__global__ __launch_bounds__(256) void router_kernel(
    const float* __restrict__ x, const float* __restrict__ rw,
    const float* __restrict__ rb, const float* __restrict__ b2,
    short* __restrict__ xb, float* __restrict__ out,
    int2* __restrict__ meta_e, float2* __restrict__ meta_p) {
  int wave = threadIdx.x >> 6;
  int lane = threadIdx.x & 63;
  int t = blockIdx.x * 4 + wave;
  if (t >= TOKENS) return;
  const float* xr = x + (size_t)t * Dm;
  short* xbr = xb + (size_t)t * Dm;
  float acc[Em];
  #pragma unroll
  for (int e = 0; e < Em; e++) acc[e] = 0.f;
  #pragma unroll
  for (int i = 0; i < 3; i++) {
    int d = i * 256 + lane * 4;
    float4 v = *(const float4*)(xr + d);
    short4v s;
    s[0] = f2b(v.x); s[1] = f2b(v.y); s[2] = f2b(v.z); s[3] = f2b(v.w);
    *(short4v*)(xbr + d) = s;
    #pragma unroll
    for (int j = 0; j < 4; j++) {
      float xv = (j == 0) ? v.x : (j == 1) ? v.y : (j == 2) ? v.z : v.w;
      const float4* rwp = (const float4*)(rw + (size_t)(d + j) * Em);
      float4 a = rwp[0], b = rwp[1];
      acc[0] += xv * a.x; acc[1] += xv * a.y; acc[2] += xv * a.z; acc[3] += xv * a.w;
      acc[4] += xv * b.x; acc[5] += xv * b.y; acc[6] += xv * b.z; acc[7] += xv * b.w;
    }
  }
  #pragma unroll
  for (int e = 0; e < Em; e++) {
    float v = acc[e];
    #pragma unroll
    for (int s = 32; s > 0; s >>= 1) v += __shfl_xor(v, s);
    acc[e] = v + rb[e];
  }
  int i1 = 0; float m1 = acc[0];
  #pragma unroll
  for (int e = 1; e < Em; e++) if (acc[e] > m1) { m1 = acc[e]; i1 = e; }
  int i2 = -1; float m2 = -1e30f;
  #pragma unroll
  for (int e = 0; e < Em; e++) if (e != i1 && acc[e] > m2) { m2 = acc[e]; i2 = e; }
  float tt = expf(m2 - m1);
  float p0 = 1.f / (1.f + tt);
  float p1 = tt / (1.f + tt);
  // out init (every launch — harness does not re-poison between replays)
  const float4* ba = (const float4*)(b2 + (size_t)i1 * Dm);
  const float4* bb = (const float4*)(b2 + (size_t)i2 * Dm);
  float4* orow = (float4*)(out + (size_t)t * Dm);
  #pragma unroll
  for (int i = 0; i < 3; i++) {
    int idx = lane + 64 * i;
    float4 a = ba[idx], b = bb[idx];
    float4 o;
    o.x = p0 * a.x + p1 * b.x; o.y = p0 * a.y + p1 * b.y;
    o.z = p0 * a.z + p1 * b.z; o.w = p0 * a.w + p1 * b.w;
    orow[idx] = o;
  }
  if (lane == 0) {
    meta_e[t] = make_int2(i1, i2);
    meta_p[t] = make_float2(p0, p1);
  }
}

// ---------------- scatter: hierarchical (LDS ranks + 8 global atomics/block) ----------------
__global__ __launch_bounds__(256) void scatter_kernel(
    const int2* __restrict__ meta_e, const float2* __restrict__ meta_p,
    int* __restrict__ cnt, int* __restrict__ list, float* __restrict__ wlist) {
  __shared__ int lcnt[Em];
  __shared__ int gbase[Em];
  int t = blockIdx.x * 256 + threadIdx.x;
  if (threadIdx.x < Em) lcnt[threadIdx.x] = 0;
  __syncthreads();
  int2 e = meta_e[t];
  float2 p = meta_p[t];
  int r0 = atomicAdd(&lcnt[e.x], 1);
  int r1 = atomicAdd(&lcnt[e.y], 1);
  __syncthreads();
  if (threadIdx.x < Em) gbase[threadIdx.x] = atomicAdd(&cnt[threadIdx.x], lcnt[threadIdx.x]);
  __syncthreads();
  int s0 = gbase[e.x] + r0;
  int s1 = gbase[e.y] + r1;
  list[e.x * TOKENS + s0] = t;  wlist[e.x * TOKENS + s0] = p.x;
  list[e.y * TOKENS + s1] = t;  wlist[e.y * TOKENS + s1] = p.y;
}

// ---------------- prefix + compact tile table (BM=128) ----------------
__global__ void prefix_kernel(const int* __restrict__ cnt, int* __restrict__ hoffs,
                              int2* __restrict__ table, int* __restrict__ ntab) {
  if (threadIdx.x == 0) {
    int s = 0, k = 0;
    for (int e = 0; e < Em; e++) {
      hoffs[e] = s;
      int c = cnt[e];
      for (int mb = 0; mb < c; mb += 128) table[k++] = make_int2(e, mb);
      s += c;
    }
    ntab[0] = k;
  }
}

// ---- grouped GEMM 128x128xBK64: counted-vmcnt dbuf schedule, 65KB LDS -> 2 blocks/CU ----
// MODE 0: h[slot] = gelu(x[tok] @ w1t^T + b1)   MODE 1: out[tok] += p * (h[slot] @ w2t^T)
// NOTE: min-waves/EU stays 2 — higher values cap VGPR and spill acc (R11: 2.04GB scratch traffic).
// NOTE: chunk order is n-INNER (consecutive same-XCD blocks share the gathered A-panel, walk
// n-tiles) — n-outer raised FETCH 202->280MB and cost +10us/GEMM (R14).
template <int MODE, int NB>
__global__ __launch_bounds__(256, 2) void moe_gemm_kernel(
    const short* __restrict__ Abase, const short* __restrict__ Wt,
    const float* __restrict__ bias, short* __restrict__ Hout,
    float* __restrict__ Out, const int* __restrict__ cnt,
    const int* __restrict__ hoffs, const int* __restrict__ list,
    const float* __restrict__ wlist, const int2* __restrict__ table,
    const int* __restrict__ ntab, int Ndim, int Kdim) {
  // XCD-chunked bijective remap (m204)
  int nwg = gridDim.x;
  int orig = blockIdx.x;
  int q8 = nwg >> 3, r8 = nwg & 7, xcd = orig & 7;
  int wg = (xcd < r8 ? xcd * (q8 + 1) : r8 * (q8 + 1) + (xcd - r8) * q8) + (orig >> 3);
  int ti = wg / NB, nt = wg % NB;
  if (ti >= ntab[0]) return;
  int2 te = table[ti];
  int e = te.x, mbase = te.y;
  int count = cnt[e], ho = hoffs[e];
  int n0 = nt * 128;

  __shared__ short As[2][128 * 64];   // 32 KiB total
  __shared__ short Bs[2][128 * 64];   // 32 KiB total  -> 65 KiB/block -> 2 blocks/CU
  __shared__ int rid_s[128];
  __shared__ float pw_s[128];

  int tid = threadIdx.x;
  if (tid < 128) {
    int rc = mbase + tid; if (rc > count - 1) rc = count - 1;
    rid_s[tid] = list[e * TOKENS + rc];
    pw_s[tid] = wlist[e * TOKENS + rc];
  }
  __syncthreads();

  // stage pointers: pass q covers rows q*32+(tid>>3); source granule pre-swizzled g ^= row&7
  const short* We = Wt + (size_t)e * Ndim * Kdim;
  const short* aptr[4];
  const short* bptr[4];
  #pragma unroll
  for (int q = 0; q < 4; q++) {
    int r = q * 32 + (tid >> 3);
    int g = (tid & 7) ^ (r & 7);
    size_t grow;
    if (MODE == 0) {
      grow = (size_t)rid_s[r] * Kdim;              // gathered token row in xbf
    } else {
      int rr = mbase + r; if (rr > count - 1) rr = count - 1;
      grow = (size_t)(ho + rr) * Kdim;             // contiguous slot row in h
    }
    aptr[q] = Abase + grow + g * 8;
    bptr[q] = We + (size_t)(n0 + r) * Kdim + g * 8;
  }
  int w = tid >> 6;

  #define STAGE(s)                                             \
    {                                                          \
      _Pragma("unroll")                                        \
      for (int q = 0; q < 4; q++) {                            \
        async16(&As[s][q * 2048 + w * 512], aptr[q]); aptr[q] += BK; \
        async16(&Bs[s][q * 2048 + w * 512], bptr[q]); bptr[q] += BK; \
      }                                                        \
    }

  int NT = Kdim / BK;
  f32x4 acc[4][4] = {};
  int lane = tid & 63;
  int wm = w >> 1, wn = w & 1;          // 2x2 waves, 64x64 output each
  int lr = lane & 15, lh = lane >> 4;
  int rsw = lr & 7;

  // prologue: two tiles in flight (R6-verified)
  STAGE(0);
  STAGE(1);
  asm volatile("s_waitcnt vmcnt(8)" ::: "memory");   // tile 0's 8 loads landed (mine)
  __builtin_amdgcn_s_barrier();

  for (int t = 0; t < NT; t++) {
    int s = t & 1;
    const short* Ab = As[s];
    const short* Bb = Bs[s];
    // kk0 fragments
    short8v a0[4], b0[4];
    #pragma unroll
    for (int m = 0; m < 4; m++)
      a0[m] = *(const short8v*)&Ab[(wm * 64 + m * 16 + lr) * 64 + (lh ^ rsw) * 8];
    #pragma unroll
    for (int n = 0; n < 4; n++)
      b0[n] = *(const short8v*)&Bb[(wn * 64 + n * 16 + lr) * 64 + (lh ^ rsw) * 8];
    __builtin_amdgcn_s_setprio(1);
    #pragma unroll
    for (int m = 0; m < 4; m++)
      #pragma unroll
      for (int n = 0; n < 4; n++)
        acc[m][n] = __builtin_amdgcn_mfma_f32_16x16x32_bf16(a0[m], b0[n], acc[m][n], 0, 0, 0);
    __builtin_amdgcn_s_setprio(0);
    // kk1 fragments (into registers BEFORE slot s is recycled)
    short8v a1[4], b1v[4];
    #pragma unroll
    for (int m = 0; m < 4; m++)
      a1[m] = *(const short8v*)&Ab[(wm * 64 + m * 16 + lr) * 64 + ((4 + lh) ^ rsw) * 8];
    #pragma unroll
    for (int n = 0; n < 4; n++)
      b1v[n] = *(const short8v*)&Bb[(wn * 64 + n * 16 + lr) * 64 + ((4 + lh) ^ rsw) * 8];
    // all slot-s reads complete; barrier => every wave done with slot s
    asm volatile("s_waitcnt lgkmcnt(0)" ::: "memory");
    __builtin_amdgcn_sched_barrier(0);
    __builtin_amdgcn_s_barrier();
    if (t + 2 < NT) STAGE(s);         // overwrite slot s with tile t+2 (registers hold kk1)
    __builtin_amdgcn_s_setprio(1);
    #pragma unroll
    for (int m = 0; m < 4; m++)
      #pragma unroll
      for (int n = 0; n < 4; n++)
        acc[m][n] = __builtin_amdgcn_mfma_f32_16x16x32_bf16(a1[m], b1v[n], acc[m][n], 0, 0, 0);
    __builtin_amdgcn_s_setprio(0);
    if (t + 2 < NT)
      asm volatile("s_waitcnt vmcnt(8)" ::: "memory");   // tile t+1's batch landed (mine)
    else
      asm volatile("s_waitcnt vmcnt(0)" ::: "memory");
    __builtin_amdgcn_s_barrier();     // all waves landed tile t+1 => safe to read next
  }
  #undef STAGE

  // ---------------- epilogue ----------------
  if (MODE == 0) {
    const float* be = bias + (size_t)e * Ndim;
    #pragma unroll
    for (int m = 0; m < 4; m++) {
      #pragma unroll
      for (int j = 0; j < 4; j++) {
        int r = wm * 64 + m * 16 + lh * 4 + j;
        if (mbase + r < count) {
          size_t rowoff = (size_t)(ho + mbase + r) * Ndim;
          #pragma unroll
          for (int n = 0; n < 4; n++) {
            int colg = n0 + wn * 64 + n * 16 + lr;
            float val = acc[m][n][j] + be[colg];
            // tanh-form gelu via sigmoid: gelu(x) = x / (1 + exp2(x*(c1 + c2*x^2)))
            // |err| vs exact ~3e-4; 7 VALU inst vs ~22 A&S erf (R14: VALUBusy 42->34%)
            float x2 = val * val;
            float ex = exp2f(val * fmaf(x2, -0.1029432f, -2.3022082f));
            val = __fdividef(val, 1.f + ex);
            Hout[rowoff + colg] = f2b(val);
          }
        }
      }
    }
  } else {
    #pragma unroll
    for (int m = 0; m < 4; m++) {
      #pragma unroll
      for (int j = 0; j < 4; j++) {
        int r = wm * 64 + m * 16 + lh * 4 + j;
        if (mbase + r < count) {
          float* orow = Out + (size_t)rid_s[r] * Dm;
          float p = pw_s[r];
          #pragma unroll
          for (int n = 0; n < 4; n++) {
            int colg = n0 + wn * 64 + n * 16 + lr;
            atomicAdd(&orow[colg], p * acc[m][n][j]);
          }
        }
      }
    }
  }
}

// ---------------- host ----------------
extern "C" void kernel_launch(void* const* d_in, const int* in_sizes, int n_in,
                              void* d_out, int out_size, void* d_ws, size_t ws_size,
                              hipStream_t stream) {
  const float* x  = (const float*)d_in[0];
  const float* rw = (const float*)d_in[1];
  const float* rb = (const float*)d_in[2];
  const float* w1 = (const float*)d_in[3];
  const float* b1 = (const float*)d_in[4];
  const float* w2 = (const float*)d_in[5];
  const float* b2 = (const float*)d_in[6];
  float* out = (float*)d_out;
  char* ws = (char*)d_ws;

  const size_t off_cnt    = 0;      // 32 B
  const size_t off_hoffs  = 64;     // 32 B
  const size_t off_ntab   = 128;    // 4 B
  const size_t off_table  = 192;    // 136*8 B
  const size_t off_list   = 2048;                                   // E*T*4 = 256K
  const size_t off_wlist  = off_list + (size_t)Em * TOKENS * 4;     // 256K
  const size_t off_meta_e = off_wlist + (size_t)Em * TOKENS * 4;
  const size_t off_meta_p = off_meta_e + (size_t)TOKENS * 8;
  const size_t off_xbf    = off_meta_p + (size_t)TOKENS * 8;
  const size_t off_w1t    = off_xbf + (size_t)TOKENS * Dm * 2;      // 12.6M
  const size_t off_w2t    = off_w1t + (size_t)Em * Dm * Fm * 2;     // +37.7M
  const size_t off_h      = off_w2t + (size_t)Em * Fm * Dm * 2;     // +37.7M
  const size_t needed     = off_h + (size_t)2 * TOKENS * Fm * 2;    // +100.7M
  if (ws_size < needed) return;

  int*    cnt    = (int*)(ws + off_cnt);
  int*    hoffs  = (int*)(ws + off_hoffs);
  int*    ntab   = (int*)(ws + off_ntab);
  int2*   table  = (int2*)(ws + off_table);
  int*    list   = (int*)(ws + off_list);
  float*  wlist  = (float*)(ws + off_wlist);
  int2*   meta_e = (int2*)(ws + off_meta_e);
  float2* meta_p = (float2*)(ws + off_meta_p);
  short*  xbf    = (short*)(ws + off_xbf);
  short*  w1t    = (short*)(ws + off_w1t);
  short*  w2t    = (short*)(ws + off_w2t);
  short*  h      = (short*)(ws + off_h);

  hipMemsetAsync(cnt, 0, 32, stream);
  cvt_tr_kernel<<<dim3(Fm / 64, Dm / 64, Em), 256, 0, stream>>>(w1, w1t, Dm, Fm);
  cvt_tr_kernel<<<dim3(Dm / 64, Fm / 64, Em), 256, 0, stream>>>(w2, w2t, Fm, Dm);
  router_kernel<<<TOKENS / 4, 256, 0, stream>>>(x, rw, rb, b2, xbf, out, meta_e, meta_p);
  scatter_kernel<<<TOKENS / 256, 256, 0, stream>>>(meta_e, meta_p, cnt, list, wlist);
  prefix_kernel<<<1, 64, 0, stream>>>(cnt, hoffs, table, ntab);
  moe_gemm_kernel<0, Fm / 128><<<MT_MAX * (Fm / 128), 256, 0, stream>>>(
      xbf, w1t, b1, h, nullptr, cnt, hoffs, list, wlist, table, ntab, Fm, Dm);
  moe_gemm_kernel<1, Dm / 128><<<MT_MAX * (Dm / 128), 256, 0, stream>>>(
      h, w2t, nullptr, nullptr, out, cnt, hoffs, list, wlist, table, ntab, Dm, Fm);
}